// Round 6
// baseline (515.527 us; speedup 1.0000x reference)
//
#include <hip/hip_runtime.h>
#include <hip/hip_fp16.h>

#define NEG_SLOPE 0.2f
#define EPS 1e-6f
#define D_IN 128
#define D_OUT 64

// Dual fused GEMM over both node sets in one dispatch.
// Per side: sfeat = half(X@W1), tout = X@W2, s1 = (X@W1)@a1, s2 = (X@W2)@a2.
// Thread tx owns cols {tx*4..+3} (W1 half) and {64+tx*4..+3} (W2 half):
// both Ws reads are 16B-stride contiguous -> conflict-free ds_read_b128.
__global__ __launch_bounds__(256) void gemm_score_dual(
    const float* __restrict__ x_user, const float* __restrict__ x_item,
    const float* __restrict__ W_ui_src, const float* __restrict__ W_ui_tgt,
    const float* __restrict__ W_iu_src, const float* __restrict__ W_iu_tgt,
    const float* __restrict__ a_ui, const float* __restrict__ a_iu,
    __half* __restrict__ sx_u, __half* __restrict__ sx_i,
    float* __restrict__ out_user, float* __restrict__ out_item,
    float* __restrict__ s_src_ui, float* __restrict__ t_tgt_iu,
    float* __restrict__ s_src_iu, float* __restrict__ t_tgt_ui,
    int nb_u, int N_USER, int N_ITEM)
{
    const bool is_item = (blockIdx.x >= (unsigned)nb_u);
    const float* X  = is_item ? x_item : x_user;
    const float* W1 = is_item ? W_iu_src : W_ui_src;   // -> sfeat + s1
    const float* W2 = is_item ? W_ui_tgt : W_ui_tgt;   // placeholder fixed below
    W2              = is_item ? W_ui_tgt : W_iu_tgt;   // -> tout + s2
    const float* a1 = is_item ? a_iu : a_ui;           // first half [0:64)
    const float* a2 = is_item ? (a_ui + 64) : (a_iu + 64);
    __half* sfeat   = is_item ? sx_i : sx_u;
    float* tout     = is_item ? out_item : out_user;
    float* s1       = is_item ? s_src_iu : s_src_ui;
    float* s2       = is_item ? t_tgt_ui : t_tgt_iu;
    const int N     = is_item ? N_ITEM : N_USER;
    const int br    = (is_item ? (blockIdx.x - nb_u) : blockIdx.x) * 64;

    __shared__ float Ws[32][128];   // K-chunk of [W1|W2]  (16 KB)
    __shared__ float Xs[64][36];    // 64 rows x 32 K (+4 pad) (9.2 KB)
    const int tid = threadIdx.x;
    const int tx = tid & 15;        // col group
    const int ty = tid >> 4;        // row group: rows ty*4 .. ty*4+3

    float acc[4][8];
    #pragma unroll
    for (int r = 0; r < 4; ++r)
        #pragma unroll
        for (int c = 0; c < 8; ++c) acc[r][c] = 0.f;

    for (int kt = 0; kt < D_IN; kt += 32) {
        // stage W chunk: rows kt..kt+31 of [W1|W2] -> Ws[32][128]
        #pragma unroll
        for (int i = 0; i < 4; ++i) {
            int l = tid + i * 256;          // float4 idx 0..1023
            int row = l >> 5;               // 32 f4 per row
            int c4 = (l & 31) << 2;
            const float* wsrc = (c4 < 64) ? &W1[(kt + row) * 64 + c4]
                                          : &W2[(kt + row) * 64 + (c4 - 64)];
            *(float4*)&Ws[row][c4] = *(const float4*)wsrc;
        }
        // stage X chunk: rows br..br+63, cols kt..kt+31
        #pragma unroll
        for (int i = 0; i < 2; ++i) {
            int l = tid + i * 256;          // float4 idx 0..511
            int row = l >> 3;               // 8 f4 per row
            int c4 = (l & 7) << 2;
            float4 v = make_float4(0.f, 0.f, 0.f, 0.f);
            if (br + row < N)
                v = *(const float4*)&X[(size_t)(br + row) * D_IN + kt + c4];
            *(float4*)&Xs[row][c4] = v;
        }
        __syncthreads();
        #pragma unroll 4
        for (int k = 0; k < 32; ++k) {
            float4 wa = *(const float4*)&Ws[k][tx * 4];        // conflict-free
            float4 wb = *(const float4*)&Ws[k][64 + tx * 4];   // conflict-free
            #pragma unroll
            for (int r = 0; r < 4; ++r) {
                float xv = Xs[ty * 4 + r][k];                  // broadcast
                acc[r][0] += xv * wa.x; acc[r][1] += xv * wa.y;
                acc[r][2] += xv * wa.z; acc[r][3] += xv * wa.w;
                acc[r][4] += xv * wb.x; acc[r][5] += xv * wb.y;
                acc[r][6] += xv * wb.z; acc[r][7] += xv * wb.w;
            }
        }
        __syncthreads();
    }

    // epilogue: cols tx*4..+3 -> sfeat(fp16)+s1, cols 64+tx*4..+3 -> tout+s2
    float a1v[4], a2v[4];
    #pragma unroll
    for (int c = 0; c < 4; ++c) {
        a1v[c] = a1[tx * 4 + c];
        a2v[c] = a2[tx * 4 + c];
    }

    #pragma unroll
    for (int r = 0; r < 4; ++r) {
        int row = br + ty * 4 + r;
        float sv1 = acc[r][0] * a1v[0] + acc[r][1] * a1v[1]
                  + acc[r][2] * a1v[2] + acc[r][3] * a1v[3];
        float sv2 = acc[r][4] * a2v[0] + acc[r][5] * a2v[1]
                  + acc[r][6] * a2v[2] + acc[r][7] * a2v[3];
        // reduce over the 16 tx lanes (xor bits 0..3 stay within the row group)
        sv1 += __shfl_xor(sv1, 1); sv2 += __shfl_xor(sv2, 1);
        sv1 += __shfl_xor(sv1, 2); sv2 += __shfl_xor(sv2, 2);
        sv1 += __shfl_xor(sv1, 4); sv2 += __shfl_xor(sv2, 4);
        sv1 += __shfl_xor(sv1, 8); sv2 += __shfl_xor(sv2, 8);
        if (row < N) {
            union { __half2 h[2]; uint2 u; } pk;
            pk.h[0] = __floats2half2_rn(acc[r][0], acc[r][1]);
            pk.h[1] = __floats2half2_rn(acc[r][2], acc[r][3]);
            *(uint2*)&sfeat[(size_t)row * 64 + tx * 4] = pk.u;
            *(float4*)&tout[(size_t)row * 64 + tx * 4] =
                make_float4(acc[r][4], acc[r][5], acc[r][6], acc[r][7]);
            if (tx == 0) { s1[row] = sv1; s2[row] = sv2; }
        }
    }
}

// Combined histogram over both edge types; phase-B targets offset by N_ITEM.
__global__ __launch_bounds__(256) void hist_kernel(
    const int* __restrict__ tgt_a, const int* __restrict__ tgt_b,
    int* __restrict__ cnt, int E_a, int E_b, int N_ITEM)
{
    int i = blockIdx.x * 256 + threadIdx.x;
    if (i < E_a) {
        atomicAdd(&cnt[tgt_a[i]], 1);
    } else if (i < E_a + E_b) {
        atomicAdd(&cnt[tgt_b[i - E_a] + N_ITEM], 1);
    }
}

// exclusive scan: per-block prefix (ofs) + block totals (bsum)
__global__ __launch_bounds__(256) void scan_block(
    const int* __restrict__ cnt, int* __restrict__ ofs, int* __restrict__ bsum, int N)
{
    __shared__ int tmp[256];
    int i = blockIdx.x * 256 + threadIdx.x;
    int v = (i < N) ? cnt[i] : 0;
    tmp[threadIdx.x] = v;
    __syncthreads();
    #pragma unroll
    for (int d = 1; d < 256; d <<= 1) {
        int t = (threadIdx.x >= d) ? tmp[threadIdx.x - d] : 0;
        __syncthreads();
        tmp[threadIdx.x] += t;
        __syncthreads();
    }
    if (i < N) ofs[i] = tmp[threadIdx.x] - v;
    if (threadIdx.x == 255) bsum[blockIdx.x] = tmp[255];
}

__global__ __launch_bounds__(256) void scan_bsums(int* __restrict__ bsum, int nb)
{
    __shared__ int tmp[256];
    __shared__ int carry;
    if (threadIdx.x == 0) carry = 0;
    __syncthreads();
    for (int base = 0; base < nb; base += 256) {
        int i = base + threadIdx.x;
        int v = (i < nb) ? bsum[i] : 0;
        tmp[threadIdx.x] = v;
        __syncthreads();
        #pragma unroll
        for (int d = 1; d < 256; d <<= 1) {
            int t = (threadIdx.x >= d) ? tmp[threadIdx.x - d] : 0;
            __syncthreads();
            tmp[threadIdx.x] += t;
            __syncthreads();
        }
        if (i < nb) bsum[i] = tmp[threadIdx.x] - v + carry;
        __syncthreads();
        if (threadIdx.x == 0) carry += tmp[255];
        __syncthreads();
    }
}

// Combined fill: att once per edge, CSR slot via atomic + bsum fold.
// After this, ofs[b] + bsum[b>>8] == global end of segment b.
__global__ __launch_bounds__(256) void fill_kernel(
    const int* __restrict__ edge_ui, const int* __restrict__ edge_iu,
    const float* __restrict__ s_src_ui, const float* __restrict__ t_tgt_ui,
    const float* __restrict__ s_src_iu, const float* __restrict__ t_tgt_iu,
    int* __restrict__ ofs, const int* __restrict__ bsum,
    int2* __restrict__ payload, int E_a, int E_b, int N_ITEM)
{
    int e = blockIdx.x * 256 + threadIdx.x;
    int s, t, bucket;
    float sc;
    if (e < E_a) {                       // phase A: user -> item
        s = edge_ui[e];
        t = edge_ui[E_a + e];
        sc = s_src_ui[s] + t_tgt_ui[t];
        bucket = t;
    } else if (e < E_a + E_b) {          // phase B: item -> user
        int eb = e - E_a;
        s = edge_iu[eb];
        t = edge_iu[E_b + eb];
        sc = s_src_iu[s] + t_tgt_iu[t];
        bucket = t + N_ITEM;
    } else return;
    sc = (sc > 0.f) ? sc : NEG_SLOPE * sc;
    float att = expf(sc);
    int pos = atomicAdd(&ofs[bucket], 1) + bsum[bucket >> 8];
    payload[pos] = make_int2(s, __float_as_int(att));
}

// One 64-lane wave per target node; lane l owns feature l.
// Cooperative payload load (coalesced) + shfl broadcast -> independent gathers.
__global__ __launch_bounds__(256) void gather_out(
    const int2* __restrict__ payload, const int* __restrict__ ofs,
    const int* __restrict__ bsum, const int* __restrict__ cnt,
    const __half* __restrict__ sx_u, const __half* __restrict__ sx_i,
    float* __restrict__ out_user, float* __restrict__ out_item,
    int N_ITEM, int NT)
{
    int wid = (blockIdx.x * 256 + threadIdx.x) >> 6;
    int lane = threadIdx.x & 63;
    if (wid >= NT) return;
    const bool is_item_tgt = (wid < N_ITEM);
    const __half* sfeat = is_item_tgt ? sx_u : sx_i;   // sources = other side
    float* orow = is_item_tgt ? &out_item[(size_t)wid * 64]
                              : &out_user[(size_t)(wid - N_ITEM) * 64];
    int end = ofs[wid] + bsum[wid >> 8];
    int deg = cnt[wid];
    int start = end - deg;
    float msg0 = 0.f, msg1 = 0.f, den = 0.f;
    for (int base = start; base < end; base += 64) {
        int nk = end - base; if (nk > 64) nk = 64;
        int2 p = make_int2(0, 0);
        if (base + lane < end) p = payload[base + lane];
        int k = 0;
        for (; k + 1 < nk; k += 2) {
            int  sA = __shfl(p.x, k);
            int  sB = __shfl(p.x, k + 1);
            float aA = __int_as_float(__shfl(p.y, k));
            float aB = __int_as_float(__shfl(p.y, k + 1));
            float fA = __half2float(sfeat[(size_t)sA * 64 + lane]);
            float fB = __half2float(sfeat[(size_t)sB * 64 + lane]);
            msg0 += aA * fA;
            msg1 += aB * fB;
            den += aA + aB;
        }
        if (k < nk) {
            int  sA = __shfl(p.x, k);
            float aA = __int_as_float(__shfl(p.y, k));
            msg0 += aA * __half2float(sfeat[(size_t)sA * 64 + lane]);
            den += aA;
        }
    }
    orow[lane] += (msg0 + msg1) / (den + EPS);
}

extern "C" void kernel_launch(void* const* d_in, const int* in_sizes, int n_in,
                              void* d_out, int out_size, void* d_ws, size_t ws_size,
                              hipStream_t stream) {
    const float* x_user   = (const float*)d_in[0];
    const float* x_item   = (const float*)d_in[1];
    const float* W_ui_src = (const float*)d_in[2];
    const float* W_ui_tgt = (const float*)d_in[3];
    const float* W_iu_src = (const float*)d_in[4];
    const float* W_iu_tgt = (const float*)d_in[5];
    const float* a_ui     = (const float*)d_in[6];   // [128]
    const float* a_iu     = (const float*)d_in[7];   // [128]
    const int*   edge_ui  = (const int*)d_in[8];     // [2][E]
    const int*   edge_iu  = (const int*)d_in[9];

    const int N_USER = in_sizes[0] / D_IN;
    const int N_ITEM = in_sizes[1] / D_IN;
    const int E_ui = in_sizes[8] / 2;
    const int E_iu = in_sizes[9] / 2;
    const int NMAX = (N_USER > N_ITEM) ? N_USER : N_ITEM;
    const int NT = N_ITEM + N_USER;       // combined target domain (items first)
    const int ET = E_ui + E_iu;

    float* out = (float*)d_out;
    float* out_user = out;                          // [N_USER][64]
    float* out_item = out + (size_t)N_USER * 64;    // [N_ITEM][64]

    // ---- workspace layout ----
    float* w = (float*)d_ws;
    __half* sx_u = (__half*)w;  w += (size_t)NMAX * 32;   // N*64 halves
    __half* sx_i = (__half*)w;  w += (size_t)NMAX * 32;
    float* s_src_ui = w;  w += N_USER;
    float* t_tgt_iu = w;  w += N_USER;
    float* s_src_iu = w;  w += N_ITEM;
    float* t_tgt_ui = w;  w += N_ITEM;
    int* cnt  = (int*)w;  w += NT;
    int* ofs  = (int*)w;  w += NT;
    int nb_scan = (NT + 255) / 256;
    int* bsum = (int*)w;  w += (nb_scan + 2) & ~1;   // keep 8B alignment
    int2* payload = (int2*)w;  w += (size_t)2 * ET;

    size_t need_bytes = (size_t)(w - (float*)d_ws) * sizeof(float);
    if (ws_size < need_bytes) return;  // clean, diagnosable failure

    int nb_u = (N_USER + 63) / 64;
    int nb_i = (N_ITEM + 63) / 64;

    // 1. both GEMMs in one dispatch
    gemm_score_dual<<<nb_u + nb_i, 256, 0, stream>>>(
        x_user, x_item, W_ui_src, W_ui_tgt, W_iu_src, W_iu_tgt, a_ui, a_iu,
        sx_u, sx_i, out_user, out_item,
        s_src_ui, t_tgt_iu, s_src_iu, t_tgt_ui,
        nb_u, N_USER, N_ITEM);

    // 2. combined CSR build over both edge types
    hipMemsetAsync(cnt, 0, (size_t)NT * sizeof(int), stream);
    hist_kernel<<<(ET + 255) / 256, 256, 0, stream>>>(
        edge_ui + E_ui, edge_iu + E_iu, cnt, E_ui, E_iu, N_ITEM);
    scan_block<<<nb_scan, 256, 0, stream>>>(cnt, ofs, bsum, NT);
    scan_bsums<<<1, 256, 0, stream>>>(bsum, nb_scan);
    fill_kernel<<<(ET + 255) / 256, 256, 0, stream>>>(
        edge_ui, edge_iu, s_src_ui, t_tgt_ui, s_src_iu, t_tgt_iu,
        ofs, bsum, payload, E_ui, E_iu, N_ITEM);

    // 3. combined gather + finalize
    gather_out<<<((size_t)NT * 64 + 255) / 256, 256, 0, stream>>>(
        payload, ofs, bsum, cnt, sx_u, sx_i, out_user, out_item, N_ITEM, NT);
}